// Round 9
// baseline (397.662 us; speedup 1.0000x reference)
//
#include <hip/hip_runtime.h>
#include <stdint.h>

#define N_ROWS 200000
#define NIMG   500
#define DMETA  24
#define WIDTH  32
#define HID    64
#define DEPTH  20
#define MC     32

typedef __attribute__((ext_vector_type(4))) short bf16x4;
typedef __attribute__((ext_vector_type(8))) short bf16x8;
typedef __attribute__((ext_vector_type(4))) float f32x4;

// K=16 bf16 MFMA (v_mfma_f32_16x16x16_bf16): C-layout == B-frag layout
// => register-chained GEMMs (no LDS). Direct builtin call — no __has_builtin
// guard (it evaluates false on the host pass and broke round 8's compile).
__device__ __forceinline__ f32x4 MFMA16(bf16x4 a, bf16x4 b, f32x4 c) {
    return __builtin_amdgcn_mfma_f32_16x16x16bf16_1k(a, b, c, 0, 0, 0);
}

// ws layout (bytes):
//   0      .. 64000  : sums/pooled (16000 f32)
//   64000  .. 227840 : W1^T A-frags  20 layers x 8 frags x (64 lanes x [4 hi,4 lo] shorts)
//   227840 .. 391680 : W2^T A-frags  same size
//   391680 .. 395776 : wimg^T A-frags (4 frags)
//   395776 .. 399872 : wsc^T A-frags  (4 frags)
#define OFF_W1 64000
#define OFF_W2 227840
#define OFF_WI 391680
#define OFF_WS 395776

__device__ __forceinline__ uint32_t rotl32(uint32_t x, int r) {
    return (x << r) | (x >> (32 - r));
}

// JAX partitionable threefry, key (0,42): bits(j) = x0^x1 of threefry2x32((0,42),(0,j))
__device__ __forceinline__ uint32_t tf_bits(uint32_t j) {
    const uint32_t ks1 = 42u, ks2 = 0x1BD11BDAu ^ 42u;
    uint32_t x0 = 0u, x1 = j + ks1;
#define R4(a,b,c,d) \
    x0 += x1; x1 = rotl32(x1,(a)); x1 ^= x0; \
    x0 += x1; x1 = rotl32(x1,(b)); x1 ^= x0; \
    x0 += x1; x1 = rotl32(x1,(c)); x1 ^= x0; \
    x0 += x1; x1 = rotl32(x1,(d)); x1 ^= x0;
    R4(13,15,26,6)  x0 += ks1; x1 += ks2 + 1u;
    R4(17,29,16,24) x0 += ks2; x1 += 0u + 2u;
    R4(13,15,26,6)                x1 += ks1 + 3u;
    R4(17,29,16,24) x0 += ks1; x1 += ks2 + 4u;
    R4(13,15,26,6)  x0 += ks2; x1 += 0u + 5u;
#undef R4
    return x0 ^ x1;
}

__device__ __forceinline__ float bits_to_normal(uint32_t b) {
    float f = __uint_as_float((b >> 9) | 0x3f800000u) - 1.0f;
    const float lo = -0.99999994f;
    float u = fmaxf(lo, f * 2.0f + lo);
    return 1.41421356f * erfinvf(u);
}

// split: round-half-up hi, truncated lo. |x - hi - lo| <~ 2^-16 |x|
__device__ __forceinline__ void split1(float x, short& hi, short& lo) {
    uint32_t b = __float_as_uint(x);
    uint32_t a = b + 0x8000u;
    hi = (short)(a >> 16);
    float r = x - __uint_as_float(a & 0xFFFF0000u);
    lo = (short)(__float_as_uint(r) >> 16);
}

__device__ __forceinline__ void split8p(const float* x, bf16x8& hi, bf16x8& lo) {
    uint32_t hu[4], lu[4];
#pragma unroll
    for (int p = 0; p < 4; ++p) {
        uint32_t a0 = __float_as_uint(x[2 * p]) + 0x8000u;
        uint32_t a1 = __float_as_uint(x[2 * p + 1]) + 0x8000u;
        hu[p] = __builtin_amdgcn_perm(a1, a0, 0x07060302u);
        float r0 = x[2 * p] - __uint_as_float(a0 & 0xFFFF0000u);
        float r1 = x[2 * p + 1] - __uint_as_float(a1 & 0xFFFF0000u);
        lu[p] = __builtin_amdgcn_perm(__float_as_uint(r1), __float_as_uint(r0), 0x07060302u);
    }
    __builtin_memcpy(&hi, hu, 16);
    __builtin_memcpy(&lo, lu, 16);
}

__device__ __forceinline__ void split4p(const float* x, bf16x4& hi, bf16x4& lo) {
    uint32_t hu[2], lu[2];
#pragma unroll
    for (int p = 0; p < 2; ++p) {
        uint32_t a0 = __float_as_uint(x[2 * p]) + 0x8000u;
        uint32_t a1 = __float_as_uint(x[2 * p + 1]) + 0x8000u;
        hu[p] = __builtin_amdgcn_perm(a1, a0, 0x07060302u);
        float r0 = x[2 * p] - __uint_as_float(a0 & 0xFFFF0000u);
        float r1 = x[2 * p + 1] - __uint_as_float(a1 & 0xFFFF0000u);
        lu[p] = __builtin_amdgcn_perm(__float_as_uint(r1), __float_as_uint(r0), 0x07060302u);
    }
    __builtin_memcpy(&hi, hu, 8);
    __builtin_memcpy(&lo, lu, 8);
}

__device__ __forceinline__ bf16x4 vlo(bf16x8 v) { bf16x4 r = {v[0], v[1], v[2], v[3]}; return r; }
__device__ __forceinline__ bf16x4 vhi(bf16x8 v) { bf16x4 r = {v[4], v[5], v[6], v[7]}; return r; }

// State convention everywhere: hC[t*4+r] = h[row = c][feat = 16t + 4q + r]
// (the MFMA C-layout of the transposed GEMM; identical to the K=16 B-frag layout)
__device__ __forceinline__ void mlp20_reg(
    float* hC0, float* hC1,
    const short* __restrict__ w1f, const short* __restrict__ w2f,
    const float* __restrict__ b1, const float* __restrict__ b2,
    int lane, int q) {
    const int fo = lane * 8;
#pragma unroll 1
    for (int l = 0; l < DEPTH; ++l) {
        bf16x8 s0h, s0l, s1h, s1l;
        split8p(hC0, s0h, s0l);
        split8p(hC1, s1h, s1l);
        bf16x4 c0h[2] = {vlo(s0h), vhi(s0h)}, c0l[2] = {vlo(s0l), vhi(s0l)};
        bf16x4 c1h[2] = {vlo(s1h), vhi(s1h)}, c1l[2] = {vlo(s1l), vhi(s1l)};
        float Y0[16], Y1[16];
        const short* wp1 = w1f + l * 4096;
#pragma unroll
        for (int Mt = 0; Mt < 4; ++Mt) {
            f32x4 bb = *(const f32x4*)(b1 + l * 64 + 16 * Mt + 4 * q);
            f32x4 a0 = {0.f, 0.f, 0.f, 0.f}, a1 = {0.f, 0.f, 0.f, 0.f};
#pragma unroll
            for (int Kc = 0; Kc < 2; ++Kc) {
                bf16x8 wf = *(const bf16x8*)(wp1 + (Mt * 2 + Kc) * 512 + fo);
                bf16x4 wh = vlo(wf), wl = vhi(wf);
                a0 = MFMA16(wh, c0h[Kc], a0);
                a0 = MFMA16(wh, c0l[Kc], a0);
                a0 = MFMA16(wl, c0h[Kc], a0);
                a1 = MFMA16(wh, c1h[Kc], a1);
                a1 = MFMA16(wh, c1l[Kc], a1);
                a1 = MFMA16(wl, c1h[Kc], a1);
            }
#pragma unroll
            for (int r = 0; r < 4; ++r) {
                Y0[Mt * 4 + r] = fmaxf(a0[r] + bb[r], 0.0f);
                Y1[Mt * 4 + r] = fmaxf(a1[r] + bb[r], 0.0f);
            }
        }
        bf16x8 y0h0, y0l0, y0h1, y0l1, y1h0, y1l0, y1h1, y1l1;
        split8p(Y0, y0h0, y0l0); split8p(Y0 + 8, y0h1, y0l1);
        split8p(Y1, y1h0, y1l0); split8p(Y1 + 8, y1h1, y1l1);
        bf16x4 yb0[4] = {vlo(y0h0), vhi(y0h0), vlo(y0h1), vhi(y0h1)};
        bf16x4 ys0[4] = {vlo(y0l0), vhi(y0l0), vlo(y0l1), vhi(y0l1)};
        bf16x4 yb1[4] = {vlo(y1h0), vhi(y1h0), vlo(y1h1), vhi(y1h1)};
        bf16x4 ys1[4] = {vlo(y1l0), vhi(y1l0), vlo(y1l1), vhi(y1l1)};
        const short* wp2 = w2f + l * 4096;
#pragma unroll
        for (int Mt2 = 0; Mt2 < 2; ++Mt2) {
            f32x4 bb = *(const f32x4*)(b2 + l * 32 + 16 * Mt2 + 4 * q);
            f32x4 a0, a1;
#pragma unroll
            for (int r = 0; r < 4; ++r) { a0[r] = hC0[Mt2 * 4 + r]; a1[r] = hC1[Mt2 * 4 + r]; }
#pragma unroll
            for (int Kc = 0; Kc < 4; ++Kc) {
                bf16x8 wf = *(const bf16x8*)(wp2 + (Mt2 * 4 + Kc) * 512 + fo);
                bf16x4 wh = vlo(wf), wl = vhi(wf);
                a0 = MFMA16(wh, yb0[Kc], a0);
                a0 = MFMA16(wh, ys0[Kc], a0);
                a0 = MFMA16(wl, yb0[Kc], a0);
                a1 = MFMA16(wh, yb1[Kc], a1);
                a1 = MFMA16(wh, ys1[Kc], a1);
                a1 = MFMA16(wl, yb1[Kc], a1);
            }
#pragma unroll
            for (int r = 0; r < 4; ++r) {
                hC0[Mt2 * 4 + r] = a0[r] + bb[r];
                hC1[Mt2 * 4 + r] = a1[r] + bb[r];
            }
        }
    }
}

// input chunks (B-frags) for one 16-row tile; row = tile_base + c
__device__ __forceinline__ void load_xchunks(
    const float* __restrict__ md, const float* __restrict__ iobs,
    const float* __restrict__ sig, int row, int q,
    bf16x4* bh, bf16x4* bl) {
    f32x4 x0 = *(const f32x4*)(md + (size_t)row * DMETA + 4 * q);
    float x0v[4] = {x0[0], x0[1], x0[2], x0[3]};
    float x1v[4] = {0.f, 0.f, 0.f, 0.f};
    if (q < 2) {
        f32x4 tv = *(const f32x4*)(md + (size_t)row * DMETA + 16 + 4 * q);
        x1v[0] = tv[0]; x1v[1] = tv[1]; x1v[2] = tv[2]; x1v[3] = tv[3];
    } else if (q == 2) {
        x1v[0] = iobs ? iobs[row] : 0.f;
        x1v[1] = sig ? sig[row] : 0.f;
    }
    split4p(x0v, bh[0], bl[0]);
    split4p(x1v, bh[1], bl[1]);
}

__device__ __forceinline__ void in_proj(
    const bf16x4* bh, const bf16x4* bl,
    const short* __restrict__ wf, const float* __restrict__ bias,
    float* hC, int lane, int q) {
    const int fo = lane * 8;
#pragma unroll
    for (int Mt = 0; Mt < 2; ++Mt) {
        f32x4 bb = *(const f32x4*)(bias + 16 * Mt + 4 * q);
        f32x4 a = {0.f, 0.f, 0.f, 0.f};
#pragma unroll
        for (int Kc = 0; Kc < 2; ++Kc) {
            bf16x8 wf8 = *(const bf16x8*)(wf + (Mt * 2 + Kc) * 512 + fo);
            bf16x4 wh = vlo(wf8), wl = vhi(wf8);
            a = MFMA16(wh, bh[Kc], a);
            a = MFMA16(wh, bl[Kc], a);
            a = MFMA16(wl, bh[Kc], a);
        }
#pragma unroll
        for (int r = 0; r < 4; ++r) hC[Mt * 4 + r] = a[r] + bb[r];
    }
}

// prep: zero sums; pack all weights as pre-split A-frags (hi/lo in one 16B lane-load)
__global__ __launch_bounds__(256) void prep_kernel(
    const float* __restrict__ w1, const float* __restrict__ w2,
    const float* __restrict__ wimg, const float* __restrict__ wsc,
    char* __restrict__ wsb) {
    int t = blockIdx.x * 256 + threadIdx.x;
    float* sums = (float*)wsb;
    if (t < 16000) { sums[t] = 0.0f; return; }
    t -= 16000;
    if (t < 40960) {  // W1: frag = Mt*2+Kc; A[m=c][k=16Kc+4q+j] = w1[k][16Mt+c]
        int l = t >> 11, rem = t & 2047, frag = rem >> 8, vs = rem & 255;
        int lane = vs >> 2, j = vs & 3, q = lane >> 4, c = lane & 15;
        int Mt = frag >> 1, Kc = frag & 1;
        int k = 16 * Kc + 4 * q + j, n = 16 * Mt + c;
        short h, lo; split1(w1[l * 2048 + k * 64 + n], h, lo);
        short* dst = (short*)(wsb + OFF_W1) + l * 4096 + frag * 512 + lane * 8;
        dst[j] = h; dst[4 + j] = lo;
        return;
    }
    t -= 40960;
    if (t < 40960) {  // W2: frag = Mt2*4+Kc
        int l = t >> 11, rem = t & 2047, frag = rem >> 8, vs = rem & 255;
        int lane = vs >> 2, j = vs & 3, q = lane >> 4, c = lane & 15;
        int Mt2 = frag >> 2, Kc = frag & 3;
        int k = 16 * Kc + 4 * q + j, n = 16 * Mt2 + c;
        short h, lo; split1(w2[l * 2048 + k * 32 + n], h, lo);
        short* dst = (short*)(wsb + OFF_W2) + l * 4096 + frag * 512 + lane * 8;
        dst[j] = h; dst[4 + j] = lo;
        return;
    }
    t -= 40960;
    if (t < 1024) {  // wimg (K padded 26->32)
        int frag = t >> 8, vs = t & 255, lane = vs >> 2, j = vs & 3;
        int q = lane >> 4, c = lane & 15, Mt = frag >> 1, Kc = frag & 1;
        int k = 16 * Kc + 4 * q + j, n = 16 * Mt + c;
        float v = (k < 26) ? wimg[k * 32 + n] : 0.0f;
        short h, lo; split1(v, h, lo);
        short* dst = (short*)(wsb + OFF_WI) + frag * 512 + lane * 8;
        dst[j] = h; dst[4 + j] = lo;
        return;
    }
    t -= 1024;
    if (t < 1024) {  // wsc (K padded 24->32)
        int frag = t >> 8, vs = t & 255, lane = vs >> 2, j = vs & 3;
        int q = lane >> 4, c = lane & 15, Mt = frag >> 1, Kc = frag & 1;
        int k = 16 * Kc + 4 * q + j, n = 16 * Mt + c;
        float v = (k < 24) ? wsc[k * 32 + n] : 0.0f;
        short h, lo; split1(v, h, lo);
        short* dst = (short*)(wsb + OFF_WS) + frag * 512 + lane * 8;
        dst[j] = h; dst[4 + j] = lo;
        return;
    }
}

// pass A: input proj -> mlp20 (register-chained) -> segment-sum
__global__ __launch_bounds__(128, 4) void pass_a(
    const float* __restrict__ md, const float* __restrict__ iobs,
    const float* __restrict__ sig, const float* __restrict__ bimg,
    const char* __restrict__ wsb, const float* __restrict__ b1,
    const float* __restrict__ b2, const int* __restrict__ ids,
    float* __restrict__ sums) {
    int lane = threadIdx.x & 63, w = threadIdx.x >> 6;
    int q = lane >> 4, c = lane & 15;
    int i0 = (blockIdx.x * 2 + w) * 32;

    bf16x4 bh0[2], bl0[2], bh1[2], bl1[2];
    load_xchunks(md, iobs, sig, i0 + c, q, bh0, bl0);
    load_xchunks(md, iobs, sig, i0 + 16 + c, q, bh1, bl1);

    float hC0[8], hC1[8];
    in_proj(bh0, bl0, (const short*)(wsb + OFF_WI), bimg, hC0, lane, q);
    in_proj(bh1, bl1, (const short*)(wsb + OFF_WI), bimg, hC1, lane, q);

    mlp20_reg(hC0, hC1, (const short*)(wsb + OFF_W1), (const short*)(wsb + OFF_W2),
              b1, b2, lane, q);

#pragma unroll
    for (int tile = 0; tile < 2; ++tile) {
        float* hC = tile ? hC1 : hC0;
        int tb = i0 + tile * 16;
        if (ids[tb] == ids[tb + 15]) {   // wave-uniform image
            float v[8];
#pragma unroll
            for (int r = 0; r < 8; ++r) v[r] = hC[r];
#pragma unroll
            for (int m = 1; m < 16; m <<= 1)
#pragma unroll
                for (int r = 0; r < 8; ++r) v[r] += __shfl_xor(v[r], m, 64);
            if (c == 0) {
                int id = ids[tb];
#pragma unroll
                for (int t = 0; t < 2; ++t)
#pragma unroll
                    for (int r = 0; r < 4; ++r)
                        atomicAdd(&sums[id * 32 + 16 * t + 4 * q + r], v[t * 4 + r]);
            }
        } else {
            int id = ids[tb + c];
#pragma unroll
            for (int t = 0; t < 2; ++t)
#pragma unroll
                for (int r = 0; r < 4; ++r)
                    atomicAdd(&sums[id * 32 + 16 * t + 4 * q + r], hC[t * 4 + r]);
        }
    }
}

__global__ __launch_bounds__(256) void normalize_kernel(float* __restrict__ sums,
                                                        const int* __restrict__ cnts) {
    int t = blockIdx.x * 256 + threadIdx.x;
    if (t < NIMG * WIDTH) {
        int img = t >> 5;
        float cc = (float)max(cnts[img], 1);
        sums[t] = sums[t] / cc;
    }
}

// pass B: input proj + pooled -> mlp20 -> head -> sample
__global__ __launch_bounds__(128, 4) void pass_b(
    const float* __restrict__ md, const float* __restrict__ bsc,
    const char* __restrict__ wsb, const float* __restrict__ b1,
    const float* __restrict__ b2, const float* __restrict__ wout,
    const float* __restrict__ bout, const int* __restrict__ ids,
    const float* __restrict__ pooled, float* __restrict__ out) {
    int lane = threadIdx.x & 63, w = threadIdx.x >> 6;
    int q = lane >> 4, c = lane & 15;
    int i0 = (blockIdx.x * 2 + w) * 32;

    bf16x4 bh0[2], bl0[2], bh1[2], bl1[2];
    load_xchunks(md, nullptr, nullptr, i0 + c, q, bh0, bl0);
    load_xchunks(md, nullptr, nullptr, i0 + 16 + c, q, bh1, bl1);

    float hC0[8], hC1[8];
    in_proj(bh0, bl0, (const short*)(wsb + OFF_WS), bsc, hC0, lane, q);
    in_proj(bh1, bl1, (const short*)(wsb + OFF_WS), bsc, hC1, lane, q);

#pragma unroll
    for (int tile = 0; tile < 2; ++tile) {
        float* hC = tile ? hC1 : hC0;
        int idv = ids[i0 + tile * 16 + c];
#pragma unroll
        for (int t = 0; t < 2; ++t) {
            f32x4 pv = *(const f32x4*)(pooled + idv * 32 + 16 * t + 4 * q);
#pragma unroll
            for (int r = 0; r < 4; ++r) hC[t * 4 + r] += pv[r];
        }
    }

    mlp20_reg(hC0, hC1, (const short*)(wsb + OFF_W1), (const short*)(wsb + OFF_W2),
              b1, b2, lane, q);

    // head: params[row=c] = sum_feat h * wout; reduce over q-groups
    float loc_t[2], sc_t[2];
#pragma unroll
    for (int tile = 0; tile < 2; ++tile) {
        const float* hC = tile ? hC1 : hC0;
        float p0 = 0.f, p1 = 0.f;
#pragma unroll
        for (int t = 0; t < 2; ++t) {
            f32x4 wA = *(const f32x4*)(wout + (16 * t + 4 * q) * 2);
            f32x4 wB = *(const f32x4*)(wout + (16 * t + 4 * q) * 2 + 4);
            p0 += hC[t * 4 + 0] * wA[0] + hC[t * 4 + 1] * wA[2]
                + hC[t * 4 + 2] * wB[0] + hC[t * 4 + 3] * wB[2];
            p1 += hC[t * 4 + 0] * wA[1] + hC[t * 4 + 1] * wA[3]
                + hC[t * 4 + 2] * wB[1] + hC[t * 4 + 3] * wB[3];
        }
        p0 += __shfl_xor(p0, 16, 64); p0 += __shfl_xor(p0, 32, 64);
        p1 += __shfl_xor(p1, 16, 64); p1 += __shfl_xor(p1, 32, 64);
        float loc = p0 + bout[0];
        float pb = p1 + bout[1];
        loc_t[tile] = loc;
        sc_t[tile] = fmaxf(pb, 0.0f) + log1pf(expf(-fabsf(pb))) + 1e-12f;
    }

    // sampling: lane covers row i0+(lane&31), half = lane>>5 does 16 draws
    int ro = lane & 31, half = lane >> 5, cs = ro & 15;
    float L0 = __shfl(loc_t[0], cs, 64), L1 = __shfl(loc_t[1], cs, 64);
    float S0 = __shfl(sc_t[0], cs, 64),  S1 = __shfl(sc_t[1], cs, 64);
    float L = (ro < 16) ? L0 : L1;
    float S = (ro < 16) ? S0 : S1;
    float lsg = logf(S);
    int row = i0 + ro;
    float kp = 0.0f;
    float* zrow = out + (size_t)row * MC + half * 16;
#pragma unroll 4
    for (int s4 = 0; s4 < 4; ++s4) {
        f32x4 zv;
#pragma unroll
        for (int jj = 0; jj < 4; ++jj) {
            int t = half * 16 + s4 * 4 + jj;
            uint32_t j = (uint32_t)(t * N_ROWS) + (uint32_t)row;
            float n = bits_to_normal(tf_bits(j));
            float z = fmaf(S, n, L);
            zv[jj] = z;
            kp += fmaf(-0.5f, n * n, fabsf(z));
        }
        *(f32x4*)(zrow + s4 * 4) = zv;
    }
    kp += __shfl_xor(kp, 32, 64);
    if (half == 0) {
        out[(size_t)N_ROWS * MC + row] =
            0.01f * (kp * (1.0f / 32.0f) - lsg - 0.91893853320467274f + 0.69314718055994531f);
    }
}

extern "C" void kernel_launch(void* const* d_in, const int* in_sizes, int n_in,
                              void* d_out, int out_size, void* d_ws, size_t ws_size,
                              hipStream_t stream) {
    const float* md   = (const float*)d_in[0];
    const float* iobs = (const float*)d_in[1];
    const float* sig  = (const float*)d_in[2];
    const float* wimg = (const float*)d_in[3];
    const float* bimg = (const float*)d_in[4];
    const float* wsc  = (const float*)d_in[5];
    const float* bsc  = (const float*)d_in[6];
    const float* w1   = (const float*)d_in[7];
    const float* b1   = (const float*)d_in[8];
    const float* w2   = (const float*)d_in[9];
    const float* b2   = (const float*)d_in[10];
    const float* wout = (const float*)d_in[11];
    const float* bout = (const float*)d_in[12];
    const int* ids    = (const int*)d_in[13];
    const int* cnts   = (const int*)d_in[14];
    float* out = (float*)d_out;
    char* wsb = (char*)d_ws;
    float* sums = (float*)wsb;

    const int nblk = N_ROWS / 64;  // 3125 blocks x 2 waves x 32 rows, exact
    prep_kernel<<<391, 256, 0, stream>>>(w1, w2, wimg, wsc, wsb);
    pass_a<<<nblk, 128, 0, stream>>>(md, iobs, sig, bimg, wsb, b1, b2, ids, sums);
    normalize_kernel<<<(NIMG * WIDTH + 255) / 256, 256, 0, stream>>>(sums, cnts);
    pass_b<<<nblk, 128, 0, stream>>>(md, bsc, wsb, b1, b2, wout, bout, ids, sums, out);
}